// Round 2
// baseline (811.723 us; speedup 1.0000x reference)
//
#include <hip/hip_runtime.h>
#include <math.h>

#define NPT 32768
#define NH 8
#define HD 24
#define EDIM 28
#define NHASH 3
#define NSEG 48

typedef unsigned long long u64;

// ---------------- K0: RPE weight reduction (fp64) ----------------
__global__ void k0_w(const float* wrpe, double* w64, double* cqp64) {
    int t = threadIdx.x;
    if (t < 16) {
        int h = t >> 1, c = t & 1;
        double s = 0.0;
        for (int i = 0; i < 24; i++)
            for (int j = 0; j < 8; j++)
                s += (double)wrpe[(h * 24 + i) * 16 + c * 8 + j];
        double m = s / 192.0;
        w64[t] = m * m;
        cqp64[t] = sqrt(2.0) * fabs(m);
    }
}

// ---------------- K1: LayerNorm1 (fp64) ----------------
__global__ void k1_ln(const float* x, const float* g, const float* b, double* xn) {
    int n = blockIdx.x * blockDim.x + threadIdx.x;
    if (n >= NPT) return;
    double v[24];
    double mu = 0.0;
    for (int i = 0; i < 24; i++) { v[i] = (double)x[n * 24 + i]; mu += v[i]; }
    mu /= 24.0;
    double var = 0.0;
    for (int i = 0; i < 24; i++) { double d = v[i] - mu; var += d * d; }
    var /= 24.0;
    double rstd = 1.0 / sqrt(var + 1e-5);
    for (int i = 0; i < 24; i++)
        xn[n * 24 + i] = (v[i] - mu) * rstd * (double)g[i] + (double)b[i];
}

// ---------------- K2: QKV projection + hat vectors + sort keys ----------------
__global__ __launch_bounds__(512) void k2_proj(
    const double* __restrict__ xn,
    const float* __restrict__ Wq, const float* __restrict__ Wk,
    const float* __restrict__ Wv, const float* __restrict__ coords,
    const float* __restrict__ alphas,
    const double* __restrict__ w64, const double* __restrict__ cqp64,
    float* __restrict__ qhat, float* __restrict__ khat, float* __restrict__ varr,
    u64* __restrict__ keys) {
    __shared__ double sXn[8][24];
    __shared__ double sQ[8][192], sK[8][192];
    int t = threadIdx.x;
    int base = blockIdx.x * 8;
    for (int i = t; i < 192; i += 512)
        sXn[i / 24][i % 24] = xn[(base + i / 24) * 24 + (i % 24)];
    __syncthreads();
    int wv = t >> 6, l = t & 63;
    int n = base + wv;
    const double QSCALE = 1.0 / sqrt(24.0);
    for (int cc = 0; cc < 3; cc++) {
        int j = l + cc * 64;
        double aq = 0.0, ak = 0.0, av = 0.0;
        for (int i = 0; i < 24; i++) {
            double xi = sXn[wv][i];
            aq += xi * (double)Wq[i * 192 + j];
            ak += xi * (double)Wk[i * 192 + j];
            av += xi * (double)Wv[i * 192 + j];
        }
        sQ[wv][j] = aq * QSCALE;
        sK[wv][j] = ak;
        int h = j / 24, e = j % 24;
        varr[(h * NPT + n) * 24 + e] = (float)av;
    }
    __syncthreads();
    double p0 = (double)coords[n * 3 + 1];
    double p1 = (double)coords[n * 3 + 2];
    // store q_hat / k_hat (fp32)
    for (int idx = l; idx < 224; idx += 64) {
        int h = idx / 28, e = idx % 28;
        float qv, kv;
        if (e < 24) {
            qv = (float)sQ[wv][h * 24 + e];
            kv = (float)sK[wv][h * 24 + e];
        } else if (e < 26) {
            int c = e - 24;
            float qp = (float)(cqp64[h * 2 + c] * (c ? p1 : p0));
            qv = qp; kv = qp;
        } else {
            double sqn = w64[h * 2] * p0 * p0 + w64[h * 2 + 1] * p1 * p1;
            if (e == 26) { qv = (float)(-sqn); kv = 1.0f; }
            else         { qv = 1.0f; kv = (float)(-sqn); }
        }
        qhat[(h * NPT + n) * 28 + e] = qv;
        khat[(h * NPT + n) * 28 + e] = kv;
    }
    // hash scores (fp64) -> sortable keys
    if (l < 48) {
        int r = l / 16, rem = l % 16, qk = rem / 8, h = rem % 8;
        double sqn = w64[h * 2] * p0 * p0 + w64[h * 2 + 1] * p1 * p1;
        double sc = 0.0;
        for (int e = 0; e < 28; e++) {
            double hv;
            if (e < 24) hv = qk ? sK[wv][h * 24 + e] : sQ[wv][h * 24 + e];
            else if (e < 26) { int c = e - 24; hv = cqp64[h * 2 + c] * (c ? p1 : p0); }
            else if (e == 26) hv = qk ? 1.0 : -sqn;
            else hv = qk ? -sqn : 1.0;
            sc += hv * (double)alphas[(r * 8 + h) * 28 + e];
        }
        u64 u = (u64)__double_as_longlong(sc);
        if (u >> 63) u = ~u; else u |= 0x8000000000000000ULL;
        u64 key = (u & ~(u64)32767) | (u64)n;
        keys[(u64)(qk * 24 + r * 8 + h) * NPT + n] = key;
    }
}

// ---------------- Bitonic sort: 48 segments of 32768 u64, in place ----------------
__global__ __launch_bounds__(1024) void sort_local_full(u64* keys) {
    __shared__ u64 s[8192];
    int t = threadIdx.x;
    u64 gbase = (u64)blockIdx.x * 8192;
    int segoff = (int)(gbase & 32767);
    for (int i = t; i < 8192; i += 1024) s[i] = keys[gbase + i];
    __syncthreads();
    for (int k = 2; k <= 8192; k <<= 1) {
        for (int j = k >> 1; j > 0; j >>= 1) {
            for (int p = t; p < 4096; p += 1024) {
                int i = ((p & ~(j - 1)) << 1) | (p & (j - 1));
                int l2 = i | j;
                bool up = (((segoff + i) & k) == 0);
                u64 a = s[i], b = s[l2];
                if ((a > b) == up) { s[i] = b; s[l2] = a; }
            }
            __syncthreads();
        }
    }
    for (int i = t; i < 8192; i += 1024) keys[gbase + i] = s[i];
}

__global__ __launch_bounds__(1024) void sort_local_tail(u64* keys, int k) {
    __shared__ u64 s[8192];
    int t = threadIdx.x;
    u64 gbase = (u64)blockIdx.x * 8192;
    int segoff = (int)(gbase & 32767);
    for (int i = t; i < 8192; i += 1024) s[i] = keys[gbase + i];
    __syncthreads();
    for (int j = 4096; j > 0; j >>= 1) {
        for (int p = t; p < 4096; p += 1024) {
            int i = ((p & ~(j - 1)) << 1) | (p & (j - 1));
            int l2 = i | j;
            bool up = (((segoff + i) & k) == 0);
            u64 a = s[i], b = s[l2];
            if ((a > b) == up) { s[i] = b; s[l2] = a; }
        }
        __syncthreads();
    }
    for (int i = t; i < 8192; i += 1024) keys[gbase + i] = s[i];
}

__global__ void sort_global_pass(u64* keys, int k, int j) {
    int p = blockIdx.x * blockDim.x + threadIdx.x;
    if (p >= NSEG * NPT / 2) return;
    int i = ((p & ~(j - 1)) << 1) | (p & (j - 1));
    int l2 = i | j;
    bool up = (((i & 32767) & k) == 0);
    u64 a = keys[i], b = keys[l2];
    if ((a > b) == up) { keys[i] = b; keys[l2] = a; }
}

// ---------------- K3: block attention (fp32) ----------------
__global__ __launch_bounds__(256) void k3_attn(
    const u64* __restrict__ keys, const float* __restrict__ qhat,
    const float* __restrict__ khat, const float* __restrict__ varr,
    float* __restrict__ oarr, float* __restrict__ zarr) {
    int b = blockIdx.x, h = blockIdx.y, r = blockIdx.z;
    __shared__ float qs[128][28];
    __shared__ float ks[128][28];
    __shared__ float vs[128][24];
    __shared__ int qidx[128];
    __shared__ int kidx[128];
    int t = threadIdx.x;
    int segQ = r * 8 + h, segK = 24 + r * 8 + h;
    for (int i = t; i < 128; i += 256) {
        qidx[i] = (int)(keys[(u64)segQ * NPT + b * 128 + i] & 32767ULL);
        kidx[i] = (int)(keys[(u64)segK * NPT + b * 128 + i] & 32767ULL);
    }
    __syncthreads();
    {
        int row = t >> 1, half = t & 1;
        int qi = qidx[row], ki = kidx[row];
        for (int e = half * 14; e < half * 14 + 14; e++) {
            qs[row][e] = qhat[((u64)h * NPT + qi) * 28 + e];
            ks[row][e] = khat[((u64)h * NPT + ki) * 28 + e];
        }
        for (int e = half * 12; e < half * 12 + 12; e++)
            vs[row][e] = varr[((u64)h * NPT + ki) * 24 + e];
    }
    __syncthreads();
    int qrow = t >> 1, half = t & 1;
    float qreg[28];
#pragma unroll
    for (int e = 0; e < 28; e++) qreg[e] = qs[qrow][e];
    float lg[64];
#pragma unroll
    for (int kk = 0; kk < 64; kk++) {
        int k2 = half * 64 + kk;
        float acc = 0.0f;
#pragma unroll
        for (int e = 0; e < 28; e++) acc += qreg[e] * ks[k2][e];
        lg[kk] = acc;
    }
    float m = -1e30f;
#pragma unroll
    for (int kk = 0; kk < 64; kk++) m = fmaxf(m, lg[kk]);
    float ssum = 0.0f;
    float oacc[24];
#pragma unroll
    for (int e = 0; e < 24; e++) oacc[e] = 0.0f;
#pragma unroll
    for (int kk = 0; kk < 64; kk++) {
        float pr = __expf(lg[kk] - m);
        ssum += pr;
        int k2 = half * 64 + kk;
#pragma unroll
        for (int e = 0; e < 24; e++) oacc[e] += pr * vs[k2][e];
    }
    float mo = __shfl_xor(m, 1);
    float M = fmaxf(m, mo);
    float f = __expf(m - M);
    ssum *= f;
    float stot = ssum + __shfl_xor(ssum, 1);
#pragma unroll
    for (int e = 0; e < 24; e++) {
        oacc[e] *= f;
        oacc[e] += __shfl_xor(oacc[e], 1);
    }
    float inv = 1.0f / stot;
    int oi = qidx[qrow];
    float* orow = &oarr[(((u64)r * 8 + h) * NPT + oi) * 24];
    for (int e = half * 12; e < half * 12 + 12; e++) orow[e] = oacc[e] * inv;
    if (half == 0) zarr[((u64)r * 8 + h) * NPT + oi] = M + __logf(stot);
}

// ---------------- K4: hash combine + Wo + residual + LN2 + FFN ----------------
__global__ __launch_bounds__(256) void k4_final(
    const float* __restrict__ oarr, const float* __restrict__ zarr,
    const float* __restrict__ x,
    const float* __restrict__ Wo, const float* __restrict__ bo,
    const float* __restrict__ g2, const float* __restrict__ b2,
    const float* __restrict__ W1, const float* __restrict__ b1f,
    const float* __restrict__ W2, const float* __restrict__ b2f,
    float* __restrict__ out) {
    __shared__ double attn[4][192];
    __shared__ double xrow[4][24];
    __shared__ double h2row[4][24];
    __shared__ double ffrow[4][24];
    __shared__ double stats[4][2];
    int t = threadIdx.x;
    int wv = t >> 6, l = t & 63;
    int n = blockIdx.x * 4 + wv;
    for (int cc = 0; cc < 3; cc++) {
        int j = l + cc * 64;
        int h = j / 24, e = j % 24;
        float z0 = zarr[((u64)0 * 8 + h) * NPT + n];
        float z1 = zarr[((u64)1 * 8 + h) * NPT + n];
        float z2 = zarr[((u64)2 * 8 + h) * NPT + n];
        float zm = fmaxf(z0, fmaxf(z1, z2));
        double e0 = exp((double)(z0 - zm));
        double e1 = exp((double)(z1 - zm));
        double e2 = exp((double)(z2 - zm));
        double esum = e0 + e1 + e2;
        double o0 = (double)oarr[(((u64)0 * 8 + h) * NPT + n) * 24 + e];
        double o1 = (double)oarr[(((u64)1 * 8 + h) * NPT + n) * 24 + e];
        double o2 = (double)oarr[(((u64)2 * 8 + h) * NPT + n) * 24 + e];
        attn[wv][j] = (e0 * o0 + e1 * o1 + e2 * o2) / esum;
    }
    __syncthreads();
    if (l < 48) {
        int e = l >> 1, part = l & 1;
        double acc = 0.0;
        for (int i = part * 96; i < part * 96 + 96; i++)
            acc += attn[wv][i] * (double)Wo[i * 24 + e];
        acc += __shfl_xor(acc, 1);
        if (part == 0) {
            double xv = (double)x[n * 24 + e] + acc + (double)bo[e];
            xrow[wv][e] = xv;
        }
    }
    __syncthreads();
    if (l == 0) {
        double mu = 0.0;
        for (int i = 0; i < 24; i++) mu += xrow[wv][i];
        mu /= 24.0;
        double var = 0.0;
        for (int i = 0; i < 24; i++) { double d = xrow[wv][i] - mu; var += d * d; }
        var /= 24.0;
        stats[wv][0] = mu;
        stats[wv][1] = 1.0 / sqrt(var + 1e-5);
    }
    __syncthreads();
    if (l < 24) {
        double h2 = (xrow[wv][l] - stats[wv][0]) * stats[wv][1] * (double)g2[l] +
                    (double)b2[l];
        h2row[wv][l] = h2;
    }
    __syncthreads();
    if (l < 24) {
        double acc = (double)b1f[l];
        for (int i = 0; i < 24; i++) acc += h2row[wv][i] * (double)W1[i * 24 + l];
        ffrow[wv][l] = acc > 0.0 ? acc : 0.0;
    }
    __syncthreads();
    if (l < 24) {
        double acc = (double)b2f[l];
        for (int i = 0; i < 24; i++) acc += ffrow[wv][i] * (double)W2[i * 24 + l];
        out[n * 24 + l] = (float)(xrow[wv][l] + acc);
    }
}

extern "C" void kernel_launch(void* const* d_in, const int* in_sizes, int n_in,
                              void* d_out, int out_size, void* d_ws, size_t ws_size,
                              hipStream_t stream) {
    const float* x      = (const float*)d_in[0];
    const float* coords = (const float*)d_in[1];
    const float* n1g    = (const float*)d_in[2];
    const float* n1b    = (const float*)d_in[3];
    const float* Wq     = (const float*)d_in[4];
    const float* Wk     = (const float*)d_in[5];
    const float* Wv     = (const float*)d_in[6];
    const float* wrpe   = (const float*)d_in[7];
    const float* Wo     = (const float*)d_in[8];
    const float* bo     = (const float*)d_in[9];
    const float* n2g    = (const float*)d_in[10];
    const float* n2b    = (const float*)d_in[11];
    const float* W1     = (const float*)d_in[12];
    const float* b1     = (const float*)d_in[13];
    const float* W2     = (const float*)d_in[14];
    const float* b2     = (const float*)d_in[15];
    const float* alphas = (const float*)d_in[16];

    char* ws = (char*)d_ws;
    size_t off = 0;
    auto alloc = [&](size_t bytes) -> void* {
        void* p = ws + off;
        off = (off + bytes + 255) & ~(size_t)255;
        return p;
    };
    double* xn    = (double*)alloc((size_t)NPT * 24 * 8);
    double* w64   = (double*)alloc(256);
    double* cqp   = (double*)alloc(256);
    float*  qhat  = (float*)alloc((size_t)NH * NPT * 28 * 4);
    float*  khat  = (float*)alloc((size_t)NH * NPT * 28 * 4);
    float*  varr  = (float*)alloc((size_t)NH * NPT * 24 * 4);
    u64*    keys  = (u64*)alloc((size_t)NSEG * NPT * 8);
    float*  oarr  = (float*)alloc((size_t)NHASH * NH * NPT * 24 * 4);
    float*  zarr  = (float*)alloc((size_t)NHASH * NH * NPT * 4);
    if (off > ws_size) return;  // workspace too small — fail loudly via wrong output

    k0_w<<<1, 64, 0, stream>>>(wrpe, w64, cqp);
    k1_ln<<<NPT / 256, 256, 0, stream>>>(x, n1g, n1b, xn);
    k2_proj<<<NPT / 8, 512, 0, stream>>>(xn, Wq, Wk, Wv, coords, alphas, w64, cqp,
                                         qhat, khat, varr, keys);
    sort_local_full<<<192, 1024, 0, stream>>>(keys);
    sort_global_pass<<<3072, 256, 0, stream>>>(keys, 16384, 8192);
    sort_local_tail<<<192, 1024, 0, stream>>>(keys, 16384);
    sort_global_pass<<<3072, 256, 0, stream>>>(keys, 32768, 16384);
    sort_global_pass<<<3072, 256, 0, stream>>>(keys, 32768, 8192);
    sort_local_tail<<<192, 1024, 0, stream>>>(keys, 32768);
    dim3 g3(256, 8, 3);
    k3_attn<<<g3, 256, 0, stream>>>(keys, qhat, khat, varr, oarr, zarr);
    k4_final<<<NPT / 4, 256, 0, stream>>>(oarr, zarr, x, Wo, bo, n2g, n2b,
                                          W1, b1, W2, b2, (float*)d_out);
}

// Round 3
// 492.093 us; speedup vs baseline: 1.6495x; 1.6495x over previous
//
#include <hip/hip_runtime.h>
#include <math.h>

#define NPT 32768
#define NH 8
#define HD 24
#define EDIM 28
#define NHASH 3
#define NSEG 48

typedef unsigned long long u64;
typedef unsigned short ushort;
typedef __attribute__((__vector_size__(8 * sizeof(short)))) short bf16x8;
typedef __attribute__((__vector_size__(4 * sizeof(float)))) float floatx4;

__device__ __forceinline__ ushort f2bf(float f) {
    unsigned u = __float_as_uint(f);
    unsigned r = u + 0x7FFF + ((u >> 16) & 1);
    return (ushort)(r >> 16);
}

// ---------------- K0: RPE weight reduction (fp64) ----------------
__global__ void k0_w(const float* wrpe, double* w64, double* cqp64) {
    int t = threadIdx.x;
    if (t < 16) {
        int h = t >> 1, c = t & 1;
        double s = 0.0;
        for (int i = 0; i < 24; i++)
            for (int j = 0; j < 8; j++)
                s += (double)wrpe[(h * 24 + i) * 16 + c * 8 + j];
        double m = s / 192.0;
        w64[t] = m * m;
        cqp64[t] = sqrt(2.0) * fabs(m);
    }
}

// ---------------- K1: LayerNorm1 (fp64) ----------------
__global__ void k1_ln(const float* x, const float* g, const float* b, double* xn) {
    int n = blockIdx.x * blockDim.x + threadIdx.x;
    if (n >= NPT) return;
    double v[24];
    double mu = 0.0;
    for (int i = 0; i < 24; i++) { v[i] = (double)x[n * 24 + i]; mu += v[i]; }
    mu /= 24.0;
    double var = 0.0;
    for (int i = 0; i < 24; i++) { double d = v[i] - mu; var += d * d; }
    var /= 24.0;
    double rstd = 1.0 / sqrt(var + 1e-5);
    for (int i = 0; i < 24; i++)
        xn[n * 24 + i] = (v[i] - mu) * rstd * (double)g[i] + (double)b[i];
}

// ---------------- K2: QKV projection + bf16 hat vectors + fp64 sort keys ----------------
__global__ __launch_bounds__(512) void k2_proj(
    const double* __restrict__ xn,
    const float* __restrict__ Wq, const float* __restrict__ Wk,
    const float* __restrict__ Wv, const float* __restrict__ coords,
    const float* __restrict__ alphas,
    const double* __restrict__ w64, const double* __restrict__ cqp64,
    ushort* __restrict__ qhatB, ushort* __restrict__ khatB, ushort* __restrict__ varrB,
    u64* __restrict__ keys) {
    __shared__ double sXn[8][24];
    __shared__ double sQ[8][192], sK[8][192];
    int t = threadIdx.x;
    int base = blockIdx.x * 8;
    for (int i = t; i < 192; i += 512)
        sXn[i / 24][i % 24] = xn[(base + i / 24) * 24 + (i % 24)];
    __syncthreads();
    int wv = t >> 6, l = t & 63;
    int n = base + wv;
    const double QSCALE = 1.0 / sqrt(24.0);
    for (int cc = 0; cc < 3; cc++) {
        int j = l + cc * 64;
        double aq = 0.0, ak = 0.0, av = 0.0;
        for (int i = 0; i < 24; i++) {
            double xi = sXn[wv][i];
            aq += xi * (double)Wq[i * 192 + j];
            ak += xi * (double)Wk[i * 192 + j];
            av += xi * (double)Wv[i * 192 + j];
        }
        sQ[wv][j] = aq * QSCALE;
        sK[wv][j] = ak;
        int h = j / 24, e = j % 24;
        varrB[((u64)h * NPT + n) * 24 + e] = f2bf((float)av);
    }
    __syncthreads();
    double p0 = (double)coords[n * 3 + 1];
    double p1 = (double)coords[n * 3 + 2];
    // store q_hat / k_hat (bf16, rows padded to 32 with zeros)
    for (int idx = l; idx < 256; idx += 64) {
        int h = idx / 32, e = idx % 32;
        float qv, kv;
        if (e < 24) {
            qv = (float)sQ[wv][h * 24 + e];
            kv = (float)sK[wv][h * 24 + e];
        } else if (e < 26) {
            int c = e - 24;
            float qp = (float)(cqp64[h * 2 + c] * (c ? p1 : p0));
            qv = qp; kv = qp;
        } else if (e < 28) {
            double sqn = w64[h * 2] * p0 * p0 + w64[h * 2 + 1] * p1 * p1;
            if (e == 26) { qv = (float)(-sqn); kv = 1.0f; }
            else         { qv = 1.0f; kv = (float)(-sqn); }
        } else {
            qv = 0.0f; kv = 0.0f;
        }
        qhatB[((u64)h * NPT + n) * 32 + e] = f2bf(qv);
        khatB[((u64)h * NPT + n) * 32 + e] = f2bf(kv);
    }
    // hash scores (fp64) -> sortable keys
    if (l < 48) {
        int r = l / 16, rem = l % 16, qk = rem / 8, h = rem % 8;
        double sqn = w64[h * 2] * p0 * p0 + w64[h * 2 + 1] * p1 * p1;
        double sc = 0.0;
        for (int e = 0; e < 28; e++) {
            double hv;
            if (e < 24) hv = qk ? sK[wv][h * 24 + e] : sQ[wv][h * 24 + e];
            else if (e < 26) { int c = e - 24; hv = cqp64[h * 2 + c] * (c ? p1 : p0); }
            else if (e == 26) hv = qk ? 1.0 : -sqn;
            else hv = qk ? -sqn : 1.0;
            sc += hv * (double)alphas[(r * 8 + h) * 28 + e];
        }
        u64 u = (u64)__double_as_longlong(sc);
        if (u >> 63) u = ~u; else u |= 0x8000000000000000ULL;
        u64 key = (u & ~(u64)32767) | (u64)n;
        keys[(u64)(qk * 24 + r * 8 + h) * NPT + n] = key;
    }
}

// ---------------- Bitonic sort: 48 segments of 32768 u64, in place ----------------
__global__ __launch_bounds__(1024) void sort_local_full(u64* keys) {
    __shared__ u64 s[8192];
    int t = threadIdx.x;
    u64 gbase = (u64)blockIdx.x * 8192;
    int segoff = (int)(gbase & 32767);
    for (int i = t; i < 8192; i += 1024) s[i] = keys[gbase + i];
    __syncthreads();
    for (int k = 2; k <= 8192; k <<= 1) {
        for (int j = k >> 1; j > 0; j >>= 1) {
            for (int p = t; p < 4096; p += 1024) {
                int i = ((p & ~(j - 1)) << 1) | (p & (j - 1));
                int l2 = i | j;
                bool up = (((segoff + i) & k) == 0);
                u64 a = s[i], b = s[l2];
                if ((a > b) == up) { s[i] = b; s[l2] = a; }
            }
            __syncthreads();
        }
    }
    for (int i = t; i < 8192; i += 1024) keys[gbase + i] = s[i];
}

__global__ __launch_bounds__(1024) void sort_local_tail(u64* keys, int k) {
    __shared__ u64 s[8192];
    int t = threadIdx.x;
    u64 gbase = (u64)blockIdx.x * 8192;
    int segoff = (int)(gbase & 32767);
    for (int i = t; i < 8192; i += 1024) s[i] = keys[gbase + i];
    __syncthreads();
    for (int j = 4096; j > 0; j >>= 1) {
        for (int p = t; p < 4096; p += 1024) {
            int i = ((p & ~(j - 1)) << 1) | (p & (j - 1));
            int l2 = i | j;
            bool up = (((segoff + i) & k) == 0);
            u64 a = s[i], b = s[l2];
            if ((a > b) == up) { s[i] = b; s[l2] = a; }
        }
        __syncthreads();
    }
    for (int i = t; i < 8192; i += 1024) keys[gbase + i] = s[i];
}

__global__ void sort_global_pass(u64* keys, int k, int j) {
    int p = blockIdx.x * blockDim.x + threadIdx.x;
    if (p >= NSEG * NPT / 2) return;
    int i = ((p & ~(j - 1)) << 1) | (p & (j - 1));
    int l2 = i | j;
    bool up = (((i & 32767) & k) == 0);
    u64 a = keys[i], b = keys[l2];
    if ((a > b) == up) { keys[i] = b; keys[l2] = a; }
}

// ---------------- K3: block attention via bf16 MFMA ----------------
// LDS: sVt[24][136] bf16, sP[128][136] bf16, qidx[128], kidx[128]
#define VT_STRIDE 136
#define P_STRIDE 136
__global__ __launch_bounds__(256) void k3_attn(
    const u64* __restrict__ keys, const ushort* __restrict__ qhatB,
    const ushort* __restrict__ khatB, const ushort* __restrict__ varrB,
    float* __restrict__ oarr, float* __restrict__ zarr) {
    int b = blockIdx.x, h = blockIdx.y, r = blockIdx.z;
    __shared__ __align__(16) char smem[6528 + 34816 + 1024];
    short* sVt = (short*)smem;                         // 24 x 136 (tile-2 pad rows read into sP: harmless)
    short* sP  = (short*)(smem + 6528);                // 128 x 136
    int* qidx  = (int*)(smem + 6528 + 34816);
    int* kidx  = qidx + 128;
    int t = threadIdx.x;
    int segQ = r * 8 + h, segK = 24 + r * 8 + h;
    if (t < 128) {
        qidx[t] = (int)(keys[(u64)segQ * NPT + b * 128 + t] & 32767ULL);
    } else {
        int i = t - 128;
        kidx[i] = (int)(keys[(u64)segK * NPT + b * 128 + i] & 32767ULL);
    }
    __syncthreads();
    // stage V transposed: sVt[e][row]
    if (t < 128) {
        int ki = kidx[t];
        const ushort* vr = varrB + ((u64)h * NPT + ki) * 24;
        ushort vv[24];
#pragma unroll
        for (int e = 0; e < 24; e++) vv[e] = vr[e];
#pragma unroll
        for (int e = 0; e < 24; e++) sVt[e * VT_STRIDE + t] = (short)vv[e];
    }
    __syncthreads();

    int wave = t >> 6, L = t & 63;
    int quad = L >> 4, n16 = L & 15;

    // ---- logits: S = Q K^T, 2 row-tiles x 8 col-tiles of 16x16, K=32 ----
    const bf16x8* Qg = (const bf16x8*)(qhatB + (u64)h * NPT * 32);
    const bf16x8* Kg = (const bf16x8*)(khatB + (u64)h * NPT * 32);
    bf16x8 afr[2];
#pragma unroll
    for (int rtg = 0; rtg < 2; rtg++) {
        int qi = qidx[wave * 32 + rtg * 16 + n16];
        afr[rtg] = Qg[(u64)qi * 4 + quad];
    }
    bf16x8 bfr[8];
#pragma unroll
    for (int ct = 0; ct < 8; ct++) {
        int ki = kidx[ct * 16 + n16];
        bfr[ct] = Kg[(u64)ki * 4 + quad];
    }
    floatx4 acc[2][8];
#pragma unroll
    for (int rtg = 0; rtg < 2; rtg++)
#pragma unroll
        for (int ct = 0; ct < 8; ct++)
            acc[rtg][ct] = (floatx4){0.f, 0.f, 0.f, 0.f};
#pragma unroll
    for (int ct = 0; ct < 8; ct++) {
#pragma unroll
        for (int rtg = 0; rtg < 2; rtg++)
            acc[rtg][ct] = __builtin_amdgcn_mfma_f32_16x16x32_bf16(afr[rtg], bfr[ct], acc[rtg][ct], 0, 0, 0);
    }

    // ---- softmax (rows in C-layout: row = wave*32 + rtg*16 + quad*4 + rg, col = ct*16+n16) ----
    float mrow[2][4], srow[2][4];
#pragma unroll
    for (int rtg = 0; rtg < 2; rtg++) {
#pragma unroll
        for (int rg = 0; rg < 4; rg++) {
            float m = -1e30f;
#pragma unroll
            for (int ct = 0; ct < 8; ct++) m = fmaxf(m, acc[rtg][ct][rg]);
            m = fmaxf(m, __shfl_xor(m, 1));
            m = fmaxf(m, __shfl_xor(m, 2));
            m = fmaxf(m, __shfl_xor(m, 4));
            m = fmaxf(m, __shfl_xor(m, 8));
            mrow[rtg][rg] = m;
            float s = 0.0f;
            int row = wave * 32 + rtg * 16 + quad * 4 + rg;
#pragma unroll
            for (int ct = 0; ct < 8; ct++) {
                float p = __expf(acc[rtg][ct][rg] - m);
                s += p;
                sP[row * P_STRIDE + ct * 16 + n16] = (short)f2bf(p);
            }
            s += __shfl_xor(s, 1);
            s += __shfl_xor(s, 2);
            s += __shfl_xor(s, 4);
            s += __shfl_xor(s, 8);
            srow[rtg][rg] = s;
        }
    }
    // z (one writer per 16-lane group)
    if (n16 == 0) {
#pragma unroll
        for (int rtg = 0; rtg < 2; rtg++)
#pragma unroll
            for (int rg = 0; rg < 4; rg++) {
                int row = wave * 32 + rtg * 16 + quad * 4 + rg;
                int oi = qidx[row];
                zarr[(u64)segQ * NPT + oi] = mrow[rtg][rg] + __logf(srow[rtg][rg]);
            }
    }

    // ---- PV: O = P V, per wave 2 row-tiles x 2 col-tiles, K=128 in 4 steps ----
    // (each wave reads only its own sP rows; sVt was barriered above)
    floatx4 occ[2][2];
#pragma unroll
    for (int rtg = 0; rtg < 2; rtg++)
#pragma unroll
        for (int ct2 = 0; ct2 < 2; ct2++)
            occ[rtg][ct2] = (floatx4){0.f, 0.f, 0.f, 0.f};
#pragma unroll
    for (int ks = 0; ks < 4; ks++) {
        bf16x8 bv[2], av[2];
#pragma unroll
        for (int ct2 = 0; ct2 < 2; ct2++)
            bv[ct2] = *(const bf16x8*)(sVt + (ct2 * 16 + n16) * VT_STRIDE + ks * 32 + quad * 8);
#pragma unroll
        for (int rtg = 0; rtg < 2; rtg++)
            av[rtg] = *(const bf16x8*)(sP + (wave * 32 + rtg * 16 + n16) * P_STRIDE + ks * 32 + quad * 8);
#pragma unroll
        for (int rtg = 0; rtg < 2; rtg++)
#pragma unroll
            for (int ct2 = 0; ct2 < 2; ct2++)
                occ[rtg][ct2] = __builtin_amdgcn_mfma_f32_16x16x32_bf16(av[rtg], bv[ct2], occ[rtg][ct2], 0, 0, 0);
    }

    // ---- epilogue: divide by row sums, scatter to oarr ----
#pragma unroll
    for (int rtg = 0; rtg < 2; rtg++) {
#pragma unroll
        for (int rg = 0; rg < 4; rg++) {
            int row = wave * 32 + rtg * 16 + quad * 4 + rg;
            int oi = qidx[row];
            float inv = 1.0f / srow[rtg][rg];
            float* orow = &oarr[((u64)segQ * NPT + oi) * 24];
#pragma unroll
            for (int ct2 = 0; ct2 < 2; ct2++) {
                int col = ct2 * 16 + n16;
                if (col < 24) orow[col] = occ[rtg][ct2][rg] * inv;
            }
        }
    }
}

// ---------------- K4: hash combine + Wo + residual + LN2 + FFN ----------------
__global__ __launch_bounds__(256) void k4_final(
    const float* __restrict__ oarr, const float* __restrict__ zarr,
    const float* __restrict__ x,
    const float* __restrict__ Wo, const float* __restrict__ bo,
    const float* __restrict__ g2, const float* __restrict__ b2,
    const float* __restrict__ W1, const float* __restrict__ b1f,
    const float* __restrict__ W2, const float* __restrict__ b2f,
    float* __restrict__ out) {
    __shared__ double attn[4][192];
    __shared__ double xrow[4][24];
    __shared__ double h2row[4][24];
    __shared__ double ffrow[4][24];
    __shared__ double stats[4][2];
    int t = threadIdx.x;
    int wv = t >> 6, l = t & 63;
    int n = blockIdx.x * 4 + wv;
    for (int cc = 0; cc < 3; cc++) {
        int j = l + cc * 64;
        int h = j / 24, e = j % 24;
        float z0 = zarr[((u64)0 * 8 + h) * NPT + n];
        float z1 = zarr[((u64)1 * 8 + h) * NPT + n];
        float z2 = zarr[((u64)2 * 8 + h) * NPT + n];
        float zm = fmaxf(z0, fmaxf(z1, z2));
        double e0 = exp((double)(z0 - zm));
        double e1 = exp((double)(z1 - zm));
        double e2 = exp((double)(z2 - zm));
        double esum = e0 + e1 + e2;
        double o0 = (double)oarr[(((u64)0 * 8 + h) * NPT + n) * 24 + e];
        double o1 = (double)oarr[(((u64)1 * 8 + h) * NPT + n) * 24 + e];
        double o2 = (double)oarr[(((u64)2 * 8 + h) * NPT + n) * 24 + e];
        attn[wv][j] = (e0 * o0 + e1 * o1 + e2 * o2) / esum;
    }
    __syncthreads();
    if (l < 48) {
        int e = l >> 1, part = l & 1;
        double acc = 0.0;
        for (int i = part * 96; i < part * 96 + 96; i++)
            acc += attn[wv][i] * (double)Wo[i * 24 + e];
        acc += __shfl_xor(acc, 1);
        if (part == 0) {
            double xv = (double)x[n * 24 + e] + acc + (double)bo[e];
            xrow[wv][e] = xv;
        }
    }
    __syncthreads();
    if (l == 0) {
        double mu = 0.0;
        for (int i = 0; i < 24; i++) mu += xrow[wv][i];
        mu /= 24.0;
        double var = 0.0;
        for (int i = 0; i < 24; i++) { double d = xrow[wv][i] - mu; var += d * d; }
        var /= 24.0;
        stats[wv][0] = mu;
        stats[wv][1] = 1.0 / sqrt(var + 1e-5);
    }
    __syncthreads();
    if (l < 24) {
        double h2 = (xrow[wv][l] - stats[wv][0]) * stats[wv][1] * (double)g2[l] +
                    (double)b2[l];
        h2row[wv][l] = h2;
    }
    __syncthreads();
    if (l < 24) {
        double acc = (double)b1f[l];
        for (int i = 0; i < 24; i++) acc += h2row[wv][i] * (double)W1[i * 24 + l];
        ffrow[wv][l] = acc > 0.0 ? acc : 0.0;
    }
    __syncthreads();
    if (l < 24) {
        double acc = (double)b2f[l];
        for (int i = 0; i < 24; i++) acc += ffrow[wv][i] * (double)W2[i * 24 + l];
        out[n * 24 + l] = (float)(xrow[wv][l] + acc);
    }
}

extern "C" void kernel_launch(void* const* d_in, const int* in_sizes, int n_in,
                              void* d_out, int out_size, void* d_ws, size_t ws_size,
                              hipStream_t stream) {
    const float* x      = (const float*)d_in[0];
    const float* coords = (const float*)d_in[1];
    const float* n1g    = (const float*)d_in[2];
    const float* n1b    = (const float*)d_in[3];
    const float* Wq     = (const float*)d_in[4];
    const float* Wk     = (const float*)d_in[5];
    const float* Wv     = (const float*)d_in[6];
    const float* wrpe   = (const float*)d_in[7];
    const float* Wo     = (const float*)d_in[8];
    const float* bo     = (const float*)d_in[9];
    const float* n2g    = (const float*)d_in[10];
    const float* n2b    = (const float*)d_in[11];
    const float* W1     = (const float*)d_in[12];
    const float* b1     = (const float*)d_in[13];
    const float* W2     = (const float*)d_in[14];
    const float* b2     = (const float*)d_in[15];
    const float* alphas = (const float*)d_in[16];

    char* ws = (char*)d_ws;
    size_t off = 0;
    auto alloc = [&](size_t bytes) -> void* {
        void* p = ws + off;
        off = (off + bytes + 255) & ~(size_t)255;
        return p;
    };
    double* xn    = (double*)alloc((size_t)NPT * 24 * 8);
    double* w64   = (double*)alloc(256);
    double* cqp   = (double*)alloc(256);
    ushort* qhatB = (ushort*)alloc((size_t)NH * NPT * 32 * 2);
    ushort* khatB = (ushort*)alloc((size_t)NH * NPT * 32 * 2);
    ushort* varrB = (ushort*)alloc((size_t)NH * NPT * 24 * 2);
    u64*    keys  = (u64*)alloc((size_t)NSEG * NPT * 8);
    float*  oarr  = (float*)alloc((size_t)NHASH * NH * NPT * 24 * 4);
    float*  zarr  = (float*)alloc((size_t)NHASH * NH * NPT * 4);
    if (off > ws_size) return;

    k0_w<<<1, 64, 0, stream>>>(wrpe, w64, cqp);
    k1_ln<<<NPT / 256, 256, 0, stream>>>(x, n1g, n1b, xn);
    k2_proj<<<NPT / 8, 512, 0, stream>>>(xn, Wq, Wk, Wv, coords, alphas, w64, cqp,
                                         qhatB, khatB, varrB, keys);
    sort_local_full<<<192, 1024, 0, stream>>>(keys);
    sort_global_pass<<<3072, 256, 0, stream>>>(keys, 16384, 8192);
    sort_local_tail<<<192, 1024, 0, stream>>>(keys, 16384);
    sort_global_pass<<<3072, 256, 0, stream>>>(keys, 32768, 16384);
    sort_global_pass<<<3072, 256, 0, stream>>>(keys, 32768, 8192);
    sort_local_tail<<<192, 1024, 0, stream>>>(keys, 32768);
    dim3 g3(256, 8, 3);
    k3_attn<<<g3, 256, 0, stream>>>(keys, qhatB, khatB, varrB, oarr, zarr);
    k4_final<<<NPT / 4, 256, 0, stream>>>(oarr, zarr, x, Wo, bo, n2g, n2b,
                                          W1, b1, W2, b2, (float*)d_out);
}